// Round 16
// baseline (409.063 us; speedup 1.0000x reference)
//
#include <hip/hip_runtime.h>
#include <math.h>

#define NCELLS 1024
#define HID 512
#define ODIM 256
#define NPAIRS 512

// counter slots
#define CNT1 0
#define CNT2 16
#define MIXC 32
#define DONE 40
#define HEADC 41

typedef __attribute__((ext_vector_type(4))) float f32x4;
typedef __attribute__((ext_vector_type(8))) short short8;
typedef unsigned short ushort_t;

__device__ inline float sigm(float x){ return 1.0f/(1.0f + expf(-x)); }
__device__ inline float tanh3(float x){ return x*fmaf(x*x, -0.33333334f, 1.0f); }
__device__ inline ushort_t f2bf(float f){
    unsigned u = __float_as_uint(f);
    return (ushort_t)((u + 0x7FFFu + ((u>>16)&1u)) >> 16);
}

// ============ K_CVT: weights/activations -> bf16 fragment order + counter init ============
__global__ __launch_bounds__(64) void k_cvt(
    const float* __restrict__ x, const float* __restrict__ hiddens,
    const float* __restrict__ W1a, const float* __restrict__ W1g,
    const float* __restrict__ W2a, const float* __restrict__ W2g,
    const float* __restrict__ w_ih, const float* __restrict__ w_hh,
    const float* __restrict__ b1a, const float* __restrict__ b1g,
    const float* __restrict__ b2a, const float* __restrict__ b2g,
    ushort_t* __restrict__ Wc1f, ushort_t* __restrict__ Wc2f,
    ushort_t* __restrict__ wihf, ushort_t* __restrict__ whhf,
    ushort_t* __restrict__ combf, ushort_t* __restrict__ hiddf,
    float* __restrict__ bc1, float* __restrict__ bc2, float* __restrict__ wcol,
    int* __restrict__ cnts)
{
    const int b = blockIdx.x;
    const int lane = threadIdx.x;
    if (b >= 5376){ // tail: scalar jobs + counter zeroing
        if (b == 5376) cnts[lane] = 0;
        int t = (b - 5376)*64 + lane;
        if (t < 256)       bc1[t] = (t<128) ? b1a[t] : b1g[t-128];
        else if (t < 512)  { int i=t-256; bc2[i] = b2a[i] - b2g[i]; }
        else               { int i=t-512; wcol[i] = w_ih[(size_t)i*257 + 256]; }
        return;
    }
    int job, idx, KT; ushort_t* dst;
    if      (b < 384){  job=0; idx=b;      KT=24; dst=Wc1f; }
    else if (b < 512){  job=1; idx=b-384;  KT=8;  dst=Wc2f; }
    else if (b < 1280){ job=2; idx=b-512;  KT=8;  dst=wihf; }
    else if (b < 2816){ job=3; idx=b-1280; KT=16; dst=whhf; }
    else if (b < 4352){ job=4; idx=b-2816; KT=24; dst=combf;}
    else             {  job=5; idx=b-4352; KT=16; dst=hiddf;}
    const int rt = idx / KT, kt = idx % KT;
    const int r  = rt*16 + (lane & 15);
    const int kb = kt*32 + (lane >> 4)*8;
    float v[8];
    if (job == 0){
        const float* s = (r < 128) ? (W1a + (size_t)r*768) : (W1g + (size_t)(r-128)*768);
        #pragma unroll
        for (int j=0;j<8;++j) v[j] = s[kb+j];
    } else if (job == 1){
        if (kb < 128){ const float* s = W2a + (size_t)r*128 + kb;
            #pragma unroll
            for (int j=0;j<8;++j) v[j] = s[j];
        } else { const float* s = W2g + (size_t)r*128 + (kb-128);
            #pragma unroll
            for (int j=0;j<8;++j) v[j] = -s[j];
        }
    } else if (job == 2){
        const float* s = w_ih + (size_t)r*257 + kb;
        #pragma unroll
        for (int j=0;j<8;++j) v[j] = s[j];
    } else if (job == 3){
        const float* s = w_hh + (size_t)r*512 + kb;
        #pragma unroll
        for (int j=0;j<8;++j) v[j] = s[j];
    } else if (job == 4){
        if (kb < 256){
            #pragma unroll
            for (int j=0;j<8;++j) v[j] = x[kb+j];
        } else { const float* s = hiddens + (size_t)r*512 + (kb-256);
            #pragma unroll
            for (int j=0;j<8;++j) v[j] = s[j];
        }
    } else {
        const float* s = hiddens + (size_t)r*512 + kb;
        #pragma unroll
        for (int j=0;j<8;++j) v[j] = s[j];
    }
    short8 o;
    #pragma unroll
    for (int j=0;j<8;++j) o[j] = (short)f2bf(v[j]);
    ((short8*)dst)[(size_t)idx*64 + lane] = o;
}

// frag-A/frag-B GEMM tile -> direct f32 store (N=1536)
__device__ inline void gemm_tile_1536(const ushort_t* Af, const ushort_t* Bf, int KT,
        const float* bias, float* C, int mtile, int nt0, int lane)
{
    const short8* A8 = (const short8*)Af;
    const short8* B8 = (const short8*)Bf;
    f32x4 acc0 = {0.f,0.f,0.f,0.f}, acc1 = {0.f,0.f,0.f,0.f};
    #pragma unroll 2
    for (int kt=0; kt<KT; ++kt){
        short8 a  = A8[((size_t)mtile*KT + kt)*64 + lane];
        short8 b0 = B8[((size_t)nt0*KT + kt)*64 + lane];
        short8 b1 = B8[((size_t)(nt0+1)*KT + kt)*64 + lane];
        acc0 = __builtin_amdgcn_mfma_f32_16x16x32_bf16(a, b0, acc0, 0,0,0);
        acc1 = __builtin_amdgcn_mfma_f32_16x16x32_bf16(a, b1, acc1, 0,0,0);
    }
    const int r0 = mtile*16 + (lane>>4)*4;
    const int c0 = nt0*16 + (lane&15);
    const float bb0 = bias[c0], bb1 = bias[c0+16];
    #pragma unroll
    for (int i=0;i<4;++i){
        C[(size_t)(r0+i)*1536 + c0]    = acc0[i] + bb0;
        C[(size_t)(r0+i)*1536 + c0+16] = acc1[i] + bb1;
    }
}

// ============ K_FRONT: L1, L2(+Of,tpart), GH, GI, tension — one kernel, counter-synced ============
__global__ __launch_bounds__(256) void k_front(
    const ushort_t* __restrict__ combf, const ushort_t* __restrict__ Wc1f,
    const float* __restrict__ bc1, ushort_t* __restrict__ H1f,
    const ushort_t* __restrict__ Wc2f, const float* __restrict__ bc2,
    float* __restrict__ OUT, ushort_t* __restrict__ Of, float* __restrict__ tpart,
    const ushort_t* __restrict__ hiddf, const ushort_t* __restrict__ whhf,
    const float* __restrict__ b_hh, float* __restrict__ GH,
    const ushort_t* __restrict__ wihf, const float* __restrict__ b_ih,
    float* __restrict__ GI, float* __restrict__ tension,
    int* __restrict__ cnts)
{
    const int xx = blockIdx.x, y = blockIdx.y;
    const int tid = threadIdx.x;
    const int lane = tid & 63, w = tid >> 6;
    const int mtile = y*4 + w;
    __shared__ float lt[4][16][33];

    if (xx < 8){
        // ---- L1 tile (xx,y) -> H1f
        {
            const int nt0 = xx*2;
            const short8* A8 = (const short8*)combf;
            const short8* B8 = (const short8*)Wc1f;
            f32x4 acc0 = {0.f,0.f,0.f,0.f}, acc1 = {0.f,0.f,0.f,0.f};
            #pragma unroll 4
            for (int kt=0; kt<24; ++kt){
                short8 a  = A8[((size_t)mtile*24 + kt)*64 + lane];
                short8 b0 = B8[((size_t)nt0*24 + kt)*64 + lane];
                short8 b1 = B8[((size_t)(nt0+1)*24 + kt)*64 + lane];
                acc0 = __builtin_amdgcn_mfma_f32_16x16x32_bf16(a, b0, acc0, 0,0,0);
                acc1 = __builtin_amdgcn_mfma_f32_16x16x32_bf16(a, b1, acc1, 0,0,0);
            }
            const int rr = (lane>>4)*4, cc = lane&15;
            const float bb0 = bc1[nt0*16 + cc], bb1 = bc1[nt0*16 + 16 + cc];
            #pragma unroll
            for (int i=0;i<4;++i){
                lt[w][rr+i][cc]    = fmaxf(acc0[i] + bb0, 0.f);
                lt[w][rr+i][16+cc] = fmaxf(acc1[i] + bb1, 0.f);
            }
            __syncthreads();
            const int m = lane & 15, kb = (lane>>4)*8;
            short8 o;
            #pragma unroll
            for (int j=0;j<8;++j) o[j] = (short)f2bf(lt[w][m][kb+j]);
            ((short8*)H1f)[((size_t)mtile*8 + xx)*64 + lane] = o;
        }
        __threadfence();
        __syncthreads();
        if (tid == 0) atomicAdd(&cnts[CNT1 + y], 1);
        // ---- GH tile (xx,y) (independent work while siblings finish L1)
        gemm_tile_1536(hiddf, whhf, 16, b_hh, GH, mtile, xx*2, lane);
        // ---- wait for row's H1f
        if (tid == 0){ while (atomicAdd(&cnts[CNT1 + y], 0) < 8) __builtin_amdgcn_s_sleep(2); }
        __syncthreads();
        __threadfence();
        // ---- L2 tile (xx,y) -> OUT, Of, tpart
        {
            const int nt0 = xx*2;
            const short8* A8 = (const short8*)H1f;
            const short8* B8 = (const short8*)Wc2f;
            f32x4 acc0 = {0.f,0.f,0.f,0.f}, acc1 = {0.f,0.f,0.f,0.f};
            #pragma unroll 4
            for (int kt=0; kt<8; ++kt){
                short8 a  = A8[((size_t)mtile*8 + kt)*64 + lane];
                short8 b0 = B8[((size_t)nt0*8 + kt)*64 + lane];
                short8 b1 = B8[((size_t)(nt0+1)*8 + kt)*64 + lane];
                acc0 = __builtin_amdgcn_mfma_f32_16x16x32_bf16(a, b0, acc0, 0,0,0);
                acc1 = __builtin_amdgcn_mfma_f32_16x16x32_bf16(a, b1, acc1, 0,0,0);
            }
            const int rr = (lane>>4)*4, cc = lane&15;
            const int c0 = nt0*16 + cc;
            const float bb0 = bc2[c0], bb1 = bc2[c0+16];
            const int r0 = mtile*16 + rr;
            #pragma unroll
            for (int i=0;i<4;++i){
                float v0 = acc0[i] + bb0;
                float v1 = acc1[i] + bb1;
                lt[w][rr+i][cc]    = v0;
                lt[w][rr+i][16+cc] = v1;
                OUT[(size_t)(r0+i)*ODIM + c0]    = v0;
                OUT[(size_t)(r0+i)*ODIM + c0+16] = v1;
            }
            __syncthreads();
            const int m = lane & 15, kb = (lane>>4)*8;
            short8 o;
            #pragma unroll
            for (int j=0;j<8;++j) o[j] = (short)f2bf(lt[w][m][kb+j]);
            ((short8*)Of)[((size_t)mtile*8 + xx)*64 + lane] = o;
            if (lane < 16){
                float s = 0.f;
                #pragma unroll
                for (int c=0;c<32;++c){ float v = lt[w][lane][c]; s = fmaf(v,v,s); }
                tpart[(size_t)xx*1024 + mtile*16 + lane] = s;
            }
        }
        __threadfence();
        __syncthreads();
        if (tid == 0) atomicAdd(&cnts[CNT2 + y], 1);
        if (tid == 0){ while (atomicAdd(&cnts[CNT2 + y], 0) < 8) __builtin_amdgcn_s_sleep(2); }
        __syncthreads();
        __threadfence();
        // ---- GI tile (xx,y)
        gemm_tile_1536(Of, wihf, 8, b_ih, GI, mtile, xx*2, lane);
        // ---- tension rows (x<4)
        if (xx < 4 && tid < 16){
            const int r = (y*4 + xx)*16 + tid;
            float s = 0.f;
            #pragma unroll
            for (int q=0;q<8;++q) s += tpart[(size_t)q*1024 + r];
            tension[r] = s * (1.0f/ODIM);
        }
    } else {
        // ---- GH tile (xx,y)
        gemm_tile_1536(hiddf, whhf, 16, b_hh, GH, mtile, xx*2, lane);
        // ---- wait for Of
        if (tid == 0){ while (atomicAdd(&cnts[CNT2 + y], 0) < 8) __builtin_amdgcn_s_sleep(2); }
        __syncthreads();
        __threadfence();
        // ---- GI tile (xx,y)
        gemm_tile_1536(Of, wihf, 8, b_ih, GI, mtile, xx*2, lane);
    }
}

// ============ K_MIXTAIL: mix (0-511) + faction fmean/final_h (512-519) + softpred (520-551) ============
__global__ __launch_bounds__(512) void k_mixtail(
    const float* __restrict__ GI, const float* __restrict__ GH,
    const float* __restrict__ tension, const float* __restrict__ wcol,
    const float* __restrict__ hiddens, const float* __restrict__ bell,
    const float* __restrict__ ent, float* __restrict__ hmix,
    float* __restrict__ fmean, const int* __restrict__ stepp,
    const float* __restrict__ OUT, float* __restrict__ copart,
    const float* __restrict__ head_w, const float* __restrict__ head_b,
    int* __restrict__ cnts, float* __restrict__ out)
{
    const int bid = blockIdx.x;
    const int tid = threadIdx.x;
    if (bid < 512){
        // ================= mix body (R11, unchanged) =================
        const int p = bid;
        const int lane = tid & 63;
        const int wv = tid >> 6;
        __shared__ __align__(16) float hi[HID], hj[HID];
        __shared__ __align__(16) float colacc[8][HID];
        {
            const int j = tid;
            const float wj0 = wcol[j], wj1 = wcol[512+j], wj2 = wcol[1024+j];
            #pragma unroll
            for (int c01=0; c01<2; ++c01){
                const int cell = 2*p + c01;
                const float tv = tension[cell];
                const float* gi = GI + (size_t)cell*1536;
                const float* gh = GH + (size_t)cell*1536;
                float rg = sigm(gi[j]      + tv*wj0 + gh[j]);
                float zg = sigm(gi[512+j]  + tv*wj1 + gh[512+j]);
                float nn = tanhf(gi[1024+j]+ tv*wj2 + rg*gh[1024+j]);
                float h  = (1.f - zg)*nn + zg*hiddens[(size_t)cell*HID + j];
                (c01 ? hj : hi)[j] = h;
            }
        }
        __syncthreads();
        const float* __restrict__ rot = bell + (size_t)p * HID * HID;
        const float e = 1.0f/(1.0f + expf(-ent[p]));
        const float one_e = 1.0f - e;
        const int c0 = lane<<2, c1 = 256 + (lane<<2);
        float hjr[8];
        #pragma unroll
        for (int k=0;k<4;++k){ hjr[k]=hj[c0+k]; hjr[4+k]=hj[c1+k]; }
        float aj[8] = {};
        #pragma unroll 2
        for (int r = wv; r < HID; r += 32) {
            const float* rp0 = rot + (size_t)r*HID;
            const float* rp1 = rot + (size_t)(r+8)*HID;
            const float* rp2 = rot + (size_t)(r+16)*HID;
            const float* rp3 = rot + (size_t)(r+24)*HID;
            float4 a0 = *(const float4*)(rp0 + c0);
            float4 a1 = *(const float4*)(rp0 + c1);
            float4 b0 = *(const float4*)(rp1 + c0);
            float4 b1 = *(const float4*)(rp1 + c1);
            float4 g0 = *(const float4*)(rp2 + c0);
            float4 g1 = *(const float4*)(rp2 + c1);
            float4 d0 = *(const float4*)(rp3 + c0);
            float4 d1 = *(const float4*)(rp3 + c1);
            float t0[8], t1[8], t2[8], t3[8];
            t0[0]=tanh3(a0.x); t0[1]=tanh3(a0.y); t0[2]=tanh3(a0.z); t0[3]=tanh3(a0.w);
            t0[4]=tanh3(a1.x); t0[5]=tanh3(a1.y); t0[6]=tanh3(a1.z); t0[7]=tanh3(a1.w);
            t1[0]=tanh3(b0.x); t1[1]=tanh3(b0.y); t1[2]=tanh3(b0.z); t1[3]=tanh3(b0.w);
            t1[4]=tanh3(b1.x); t1[5]=tanh3(b1.y); t1[6]=tanh3(b1.z); t1[7]=tanh3(b1.w);
            t2[0]=tanh3(g0.x); t2[1]=tanh3(g0.y); t2[2]=tanh3(g0.z); t2[3]=tanh3(g0.w);
            t2[4]=tanh3(g1.x); t2[5]=tanh3(g1.y); t2[6]=tanh3(g1.z); t2[7]=tanh3(g1.w);
            t3[0]=tanh3(d0.x); t3[1]=tanh3(d0.y); t3[2]=tanh3(d0.z); t3[3]=tanh3(d0.w);
            t3[4]=tanh3(d1.x); t3[5]=tanh3(d1.y); t3[6]=tanh3(d1.z); t3[7]=tanh3(d1.w);
            const float h0 = hi[r], h1 = hi[r+8], h2 = hi[r+16], h3 = hi[r+24];
            float rp_0 = 0.f, rp_1 = 0.f, rp_2 = 0.f, rp_3 = 0.f;
            #pragma unroll
            for (int k=0;k<8;++k){
                rp_0 = fmaf(t0[k], hjr[k], rp_0);
                rp_1 = fmaf(t1[k], hjr[k], rp_1);
                rp_2 = fmaf(t2[k], hjr[k], rp_2);
                rp_3 = fmaf(t3[k], hjr[k], rp_3);
                aj[k] = fmaf(t0[k], h0, fmaf(t1[k], h1, fmaf(t2[k], h2, fmaf(t3[k], h3, aj[k]))));
            }
            #pragma unroll
            for (int m=1;m<64;m<<=1){
                rp_0 += __shfl_xor(rp_0, m);
                rp_1 += __shfl_xor(rp_1, m);
                rp_2 += __shfl_xor(rp_2, m);
                rp_3 += __shfl_xor(rp_3, m);
            }
            if (lane == 0){
                float* dst = hmix + (size_t)(2*p)*HID;
                dst[r]    = one_e*h0 + e*rp_0;
                dst[r+8]  = one_e*h1 + e*rp_1;
                dst[r+16] = one_e*h2 + e*rp_2;
                dst[r+24] = one_e*h3 + e*rp_3;
            }
        }
        *(float4*)&colacc[wv][c0] = make_float4(aj[0],aj[1],aj[2],aj[3]);
        *(float4*)&colacc[wv][c1] = make_float4(aj[4],aj[5],aj[6],aj[7]);
        __syncthreads();
        float s = 0.0f;
        #pragma unroll
        for (int w=0;w<8;++w) s += colacc[w][tid];
        hmix[(size_t)(2*p+1)*HID + tid] = -(one_e*hj[tid] + e*s);
        // publish
        __threadfence();
        __syncthreads();
        if (tid == 0) atomicAdd(&cnts[MIXC + (p>>6)], 1);
        return;
    }
    if (bid < 520){
        // ================= faction fmean + final_h =================
        const int f = bid - 512;
        __shared__ float fm[HID], gm[HID];
        if (tid == 0){ while (atomicAdd(&cnts[MIXC + f], 0) < 64) __builtin_amdgcn_s_sleep(2); }
        __syncthreads();
        __threadfence();
        float s = 0.f;
        const float* hp = hmix + (size_t)f*128*HID + tid;
        for (int c=0;c<128;++c) s += hp[(size_t)c*HID];
        const float fv = s * (1.0f/128.0f);
        fm[tid] = fv;
        fmean[f*HID + tid] = fv;
        __threadfence();
        __syncthreads();
        if (tid == 0) atomicAdd(&cnts[DONE], 1);
        if (tid == 0){ while (atomicAdd(&cnts[DONE], 0) < 8) __builtin_amdgcn_s_sleep(2); }
        __syncthreads();
        __threadfence();
        float g = 0.f;
        #pragma unroll
        for (int q=0;q<8;++q) g += fmean[q*HID + tid];
        gm[tid] = g * 0.125f;
        __syncthreads();
        const int stp = *stepp;
        const float fvv = fm[tid], gvv = gm[tid];
        for (int c=0;c<128;++c){
            const int cell = f*128 + c;
            float v = 0.85f*hmix[(size_t)cell*HID + tid] + 0.15f*fvv;
            if (stp > 5 && c < 32) v = 0.85f*v + 0.15f*gvv;
            out[257 + (size_t)cell*HID + tid] = v;
        }
        return;
    }
    // ================= softpred (threads 0..255 active) =================
    {
        const int b = bid - 520;
        const int t = tid;
        __shared__ float red[4], redb[4], SS[1];
        __shared__ float wts[1024];
        __shared__ int isLast;
        __shared__ float co[ODIM];
        float4 tv = {0,0,0,0};
        float ex0=0, ex1=0, ex2=0, ex3=0;
        if (t < 256){
            tv = *(const float4*)&tension[t*4];
            float m = fmaxf(fmaxf(tv.x, tv.y), fmaxf(tv.z, tv.w));
            #pragma unroll
            for (int s=1;s<64;s<<=1) m = fmaxf(m, __shfl_xor(m, s));
            if ((t&63) == 0) red[t>>6] = m;
        }
        __syncthreads();
        if (t < 256){
            float M = fmaxf(fmaxf(red[0],red[1]), fmaxf(red[2],red[3]));
            ex0 = expf(tv.x - M); ex1 = expf(tv.y - M); ex2 = expf(tv.z - M); ex3 = expf(tv.w - M);
            float s2 = ex0+ex1+ex2+ex3;
            float s3 = tv.x+tv.y+tv.z+tv.w;
            #pragma unroll
            for (int s=1;s<64;s<<=1){ s2 += __shfl_xor(s2,s); s3 += __shfl_xor(s3,s); }
            if ((t&63) == 0){ red[t>>6] = s2; redb[t>>6] = s3; }
        }
        __syncthreads();
        if (t == 0){
            SS[0] = red[0]+red[1]+red[2]+red[3];
            if (b == 0)
                out[256] = (redb[0]+redb[1]+redb[2]+redb[3]) * (1.0f/1024.0f);
        }
        __syncthreads();
        if (t < 256){
            const float inv = 1.0f / SS[0];
            wts[t*4+0] = ex0*inv; wts[t*4+1] = ex1*inv; wts[t*4+2] = ex2*inv; wts[t*4+3] = ex3*inv;
        }
        __syncthreads();
        if (t < 256){
            float s = 0.f;
            for (int r = b*32; r < b*32+32; ++r)
                s = fmaf(wts[r], OUT[(size_t)r*ODIM + t], s);
            copart[b*ODIM + t] = s;
        }
        __threadfence();
        __syncthreads();
        if (t == 0) isLast = (atomicAdd(&cnts[HEADC], 1) == 31);
        __syncthreads();
        if (!isLast) return;
        __threadfence();
        if (t < 256){
            float s = 0.f;
            #pragma unroll
            for (int bb=0;bb<32;++bb) s += copart[bb*ODIM + t];
            co[t] = s;
        }
        __syncthreads();
        if (t < 256){
            float acc = head_b[t];
            const float4* wr = (const float4*)(head_w + (size_t)t*ODIM);
            #pragma unroll 4
            for (int c4=0;c4<64;++c4){
                float4 w4 = wr[c4];
                acc = fmaf(w4.x, co[c4*4+0], acc);
                acc = fmaf(w4.y, co[c4*4+1], acc);
                acc = fmaf(w4.z, co[c4*4+2], acc);
                acc = fmaf(w4.w, co[c4*4+3], acc);
            }
            out[t] = acc;   // pred
        }
    }
}

extern "C" void kernel_launch(void* const* d_in, const int* in_sizes, int n_in,
                              void* d_out, int out_size, void* d_ws, size_t ws_size,
                              hipStream_t stream)
{
    const float* x      = (const float*)d_in[0];
    const float* hiddens= (const float*)d_in[1];
    const float* W1a=(const float*)d_in[2];  const float* b1a=(const float*)d_in[3];
    const float* W2a=(const float*)d_in[4];  const float* b2a=(const float*)d_in[5];
    const float* W1g=(const float*)d_in[6];  const float* b1g=(const float*)d_in[7];
    const float* W2g=(const float*)d_in[8];  const float* b2g=(const float*)d_in[9];
    const float* w_ih=(const float*)d_in[10]; const float* w_hh=(const float*)d_in[11];
    const float* b_ih=(const float*)d_in[12]; const float* b_hh=(const float*)d_in[13];
    const float* head_w=(const float*)d_in[14]; const float* head_b=(const float*)d_in[15];
    const float* ent=(const float*)d_in[16]; const float* bell=(const float*)d_in[17];
    const int*   stepp=(const int*)d_in[18];
    float* out = (float*)d_out;

    char* wsb = (char*)d_ws;
    size_t off = 0;
    auto carve = [&](size_t bytes)->char*{ char* p = wsb + off; off += (bytes + 63) & ~(size_t)63; return p; };
    ushort_t* combf = (ushort_t*)carve((size_t)1024*768*2);
    ushort_t* hiddf = (ushort_t*)carve((size_t)1024*512*2);
    ushort_t* Wc1f  = (ushort_t*)carve((size_t)256*768*2);
    ushort_t* Wc2f  = (ushort_t*)carve((size_t)256*256*2);
    ushort_t* wihf  = (ushort_t*)carve((size_t)1536*256*2);
    ushort_t* whhf  = (ushort_t*)carve((size_t)1536*512*2);
    ushort_t* H1f   = (ushort_t*)carve((size_t)1024*256*2);
    ushort_t* Of    = (ushort_t*)carve((size_t)1024*256*2);
    float* bc1   = (float*)carve(256*4);
    float* bc2   = (float*)carve(256*4);
    float* wcol  = (float*)carve(1536*4);
    float* OUT   = (float*)carve((size_t)1024*256*4);
    float* tension=(float*)carve(1024*4);
    float* tpart = (float*)carve((size_t)8*1024*4);
    float* GI    = (float*)carve((size_t)1024*1536*4);
    float* GH    = (float*)carve((size_t)1024*1536*4);
    float* hmix  = (float*)carve((size_t)1024*512*4);
    float* fmean = (float*)carve(8*512*4);
    float* copart =(float*)carve(32*256*4);
    int*   cnts  = (int*)carve(64*4);

    k_cvt<<<5408, 64, 0, stream>>>(x, hiddens, W1a, W1g, W2a, W2g, w_ih, w_hh,
                                   b1a, b1g, b2a, b2g,
                                   Wc1f, Wc2f, wihf, whhf, combf, hiddf, bc1, bc2, wcol,
                                   cnts);
    k_front<<<dim3(48,16), 256, 0, stream>>>(combf, Wc1f, bc1, H1f,
                                             Wc2f, bc2, OUT, Of, tpart,
                                             hiddf, whhf, b_hh, GH,
                                             wihf, b_ih, GI, tension, cnts);
    k_mixtail<<<552, 512, 0, stream>>>(GI, GH, tension, wcol, hiddens, bell, ent, hmix,
                                       fmean, stepp, OUT, copart, head_w, head_b,
                                       cnts, out);
}

// Round 17
// 161.423 us; speedup vs baseline: 2.5341x; 2.5341x over previous
//
#include <hip/hip_runtime.h>
#include <math.h>

#define NCELLS 1024
#define HID 512
#define ODIM 256
#define NPAIRS 512

typedef __attribute__((ext_vector_type(4))) float f32x4;
typedef __attribute__((ext_vector_type(8))) short short8;
typedef unsigned short ushort_t;

__device__ inline float sigm(float x){ return 1.0f/(1.0f + expf(-x)); }
__device__ inline float tanh3(float x){ return x*fmaf(x*x, -0.33333334f, 1.0f); }
__device__ inline ushort_t f2bf(float f){
    unsigned u = __float_as_uint(f);
    return (ushort_t)((u + 0x7FFFu + ((u>>16)&1u)) >> 16);
}

// ============ K_CVT: build bf16 fragment-order operands ============
__global__ __launch_bounds__(64) void k_cvt(
    const float* __restrict__ x, const float* __restrict__ hiddens,
    const float* __restrict__ W1a, const float* __restrict__ W1g,
    const float* __restrict__ W2a, const float* __restrict__ W2g,
    const float* __restrict__ w_ih, const float* __restrict__ w_hh,
    const float* __restrict__ b1a, const float* __restrict__ b1g,
    const float* __restrict__ b2a, const float* __restrict__ b2g,
    ushort_t* __restrict__ Wc1f, ushort_t* __restrict__ Wc2f,
    ushort_t* __restrict__ wihf, ushort_t* __restrict__ whhf,
    ushort_t* __restrict__ combf, ushort_t* __restrict__ hiddf,
    float* __restrict__ bc1, float* __restrict__ bc2, float* __restrict__ wcol,
    int* __restrict__ counter)
{
    const int b = blockIdx.x;
    const int lane = threadIdx.x;
    if (b >= 5376){ // tail: scalar jobs
        if (b == 5376 && lane == 0) *counter = 0;
        int t = (b - 5376)*64 + lane;
        if (t < 256)       bc1[t] = (t<128) ? b1a[t] : b1g[t-128];
        else if (t < 512)  { int i=t-256; bc2[i] = b2a[i] - b2g[i]; }
        else               { int i=t-512; wcol[i] = w_ih[(size_t)i*257 + 256]; }
        return;
    }
    int job, idx, KT; ushort_t* dst;
    if      (b < 384){  job=0; idx=b;      KT=24; dst=Wc1f; }
    else if (b < 512){  job=1; idx=b-384;  KT=8;  dst=Wc2f; }
    else if (b < 1280){ job=2; idx=b-512;  KT=8;  dst=wihf; }
    else if (b < 2816){ job=3; idx=b-1280; KT=16; dst=whhf; }
    else if (b < 4352){ job=4; idx=b-2816; KT=24; dst=combf;}
    else             {  job=5; idx=b-4352; KT=16; dst=hiddf;}
    const int rt = idx / KT, kt = idx % KT;
    const int r  = rt*16 + (lane & 15);
    const int kb = kt*32 + (lane >> 4)*8;
    float v[8];
    if (job == 0){
        const float* s = (r < 128) ? (W1a + (size_t)r*768) : (W1g + (size_t)(r-128)*768);
        #pragma unroll
        for (int j=0;j<8;++j) v[j] = s[kb+j];
    } else if (job == 1){
        if (kb < 128){ const float* s = W2a + (size_t)r*128 + kb;
            #pragma unroll
            for (int j=0;j<8;++j) v[j] = s[j];
        } else { const float* s = W2g + (size_t)r*128 + (kb-128);
            #pragma unroll
            for (int j=0;j<8;++j) v[j] = -s[j];
        }
    } else if (job == 2){
        const float* s = w_ih + (size_t)r*257 + kb;
        #pragma unroll
        for (int j=0;j<8;++j) v[j] = s[j];
    } else if (job == 3){
        const float* s = w_hh + (size_t)r*512 + kb;
        #pragma unroll
        for (int j=0;j<8;++j) v[j] = s[j];
    } else if (job == 4){
        if (kb < 256){
            #pragma unroll
            for (int j=0;j<8;++j) v[j] = x[kb+j];
        } else { const float* s = hiddens + (size_t)r*512 + (kb-256);
            #pragma unroll
            for (int j=0;j<8;++j) v[j] = s[j];
        }
    } else {
        const float* s = hiddens + (size_t)r*512 + kb;
        #pragma unroll
        for (int j=0;j<8;++j) v[j] = s[j];
    }
    short8 o;
    #pragma unroll
    for (int j=0;j<8;++j) o[j] = (short)f2bf(v[j]);
    ((short8*)dst)[(size_t)idx*64 + lane] = o;
}

// ============ L1: H1 = relu(comb @ Wc1^T + bc1), bf16 A-frag out ============
__global__ __launch_bounds__(256) void k_mmL1(
    const ushort_t* __restrict__ combf, const ushort_t* __restrict__ Wc1f,
    const float* __restrict__ bc1, ushort_t* __restrict__ H1f)
{
    const int lane = threadIdx.x & 63;
    const int w    = threadIdx.x >> 6;
    const int mtile = blockIdx.y*4 + w;
    const int nt0   = blockIdx.x*2;
    const short8* A8 = (const short8*)combf;
    const short8* B8 = (const short8*)Wc1f;
    f32x4 acc0 = {0.f,0.f,0.f,0.f}, acc1 = {0.f,0.f,0.f,0.f};
    #pragma unroll 4
    for (int kt=0; kt<24; ++kt){
        short8 a  = A8[((size_t)mtile*24 + kt)*64 + lane];
        short8 b0 = B8[((size_t)nt0*24 + kt)*64 + lane];
        short8 b1 = B8[((size_t)(nt0+1)*24 + kt)*64 + lane];
        acc0 = __builtin_amdgcn_mfma_f32_16x16x32_bf16(a, b0, acc0, 0,0,0);
        acc1 = __builtin_amdgcn_mfma_f32_16x16x32_bf16(a, b1, acc1, 0,0,0);
    }
    __shared__ float lt[4][16][33];
    const int rr = (lane>>4)*4, cc = lane&15;
    const float bb0 = bc1[nt0*16 + cc], bb1 = bc1[nt0*16 + 16 + cc];
    #pragma unroll
    for (int i=0;i<4;++i){
        lt[w][rr+i][cc]    = fmaxf(acc0[i] + bb0, 0.f);
        lt[w][rr+i][16+cc] = fmaxf(acc1[i] + bb1, 0.f);
    }
    __syncthreads();
    const int m = lane & 15, kb = (lane>>4)*8;
    short8 o;
    #pragma unroll
    for (int j=0;j<8;++j) o[j] = (short)f2bf(lt[w][m][kb+j]);
    ((short8*)H1f)[((size_t)mtile*gridDim.x + blockIdx.x)*64 + lane] = o;
}

// ============ L2: OUT = H1 @ Wc2^T + bc2 ; also emits Of frags + tension partials ============
__global__ __launch_bounds__(256) void k_mmL2(
    const ushort_t* __restrict__ H1f, const ushort_t* __restrict__ Wc2f,
    const float* __restrict__ bc2, float* __restrict__ OUT,
    ushort_t* __restrict__ Of, float* __restrict__ tpart)
{
    const int lane = threadIdx.x & 63;
    const int w    = threadIdx.x >> 6;
    const int mtile = blockIdx.y*4 + w;
    const int nt0   = blockIdx.x*2;
    const short8* A8 = (const short8*)H1f;
    const short8* B8 = (const short8*)Wc2f;
    f32x4 acc0 = {0.f,0.f,0.f,0.f}, acc1 = {0.f,0.f,0.f,0.f};
    #pragma unroll 4
    for (int kt=0; kt<8; ++kt){
        short8 a  = A8[((size_t)mtile*8 + kt)*64 + lane];
        short8 b0 = B8[((size_t)nt0*8 + kt)*64 + lane];
        short8 b1 = B8[((size_t)(nt0+1)*8 + kt)*64 + lane];
        acc0 = __builtin_amdgcn_mfma_f32_16x16x32_bf16(a, b0, acc0, 0,0,0);
        acc1 = __builtin_amdgcn_mfma_f32_16x16x32_bf16(a, b1, acc1, 0,0,0);
    }
    __shared__ float lt[4][16][33];
    const int rr = (lane>>4)*4, cc = lane&15;
    const int c0 = nt0*16 + cc;
    const float bb0 = bc2[c0], bb1 = bc2[c0+16];
    const int r0 = mtile*16 + rr;
    #pragma unroll
    for (int i=0;i<4;++i){
        float v0 = acc0[i] + bb0;
        float v1 = acc1[i] + bb1;
        lt[w][rr+i][cc]    = v0;
        lt[w][rr+i][16+cc] = v1;
        OUT[(size_t)(r0+i)*ODIM + c0]    = v0;
        OUT[(size_t)(r0+i)*ODIM + c0+16] = v1;
    }
    __syncthreads();
    const int m = lane & 15, kb = (lane>>4)*8;
    short8 o;
    #pragma unroll
    for (int j=0;j<8;++j) o[j] = (short)f2bf(lt[w][m][kb+j]);
    ((short8*)Of)[((size_t)mtile*8 + blockIdx.x)*64 + lane] = o;
    if (lane < 16){
        float s = 0.f;
        #pragma unroll
        for (int c=0;c<32;++c){ float v = lt[w][lane][c]; s = fmaf(v,v,s); }
        tpart[(size_t)blockIdx.x*1024 + mtile*16 + lane] = s;
    }
}

// ============ K_MM2: z=0 GH, z=1 GI (frag A) ; z=2 tension reduce ============
__global__ __launch_bounds__(256) void k_mm2(
    const ushort_t* __restrict__ hiddf, const ushort_t* __restrict__ whhf,
    const float* __restrict__ b_hh, float* __restrict__ GH,
    const ushort_t* __restrict__ Of, const ushort_t* __restrict__ wihf,
    const float* __restrict__ b_ih, float* __restrict__ GI,
    const float* __restrict__ tpart, float* __restrict__ tension)
{
    const int z = blockIdx.z;
    if (z == 2){
        if (blockIdx.x >= 4) return;
        const int rt = blockIdx.y*4 + blockIdx.x;
        if (threadIdx.x < 16){
            const int r = rt*16 + threadIdx.x;
            float s = 0.f;
            #pragma unroll
            for (int q=0;q<8;++q) s += tpart[(size_t)q*1024 + r];
            tension[r] = s * (1.0f/ODIM);
        }
        return;
    }
    const ushort_t* Af = (z == 0) ? hiddf : Of;
    const ushort_t* Bf = (z == 0) ? whhf  : wihf;
    const float* bias  = (z == 0) ? b_hh  : b_ih;
    float* C           = (z == 0) ? GH    : GI;
    const int KT       = (z == 0) ? 16    : 8;
    const int lane = threadIdx.x & 63;
    const int w    = threadIdx.x >> 6;
    const int mtile = blockIdx.y*4 + w;
    const int nt0   = blockIdx.x*2;
    const short8* A8 = (const short8*)Af;
    const short8* B8 = (const short8*)Bf;
    f32x4 acc0 = {0.f,0.f,0.f,0.f}, acc1 = {0.f,0.f,0.f,0.f};
    #pragma unroll 2
    for (int kt=0; kt<KT; ++kt){
        short8 a  = A8[((size_t)mtile*KT + kt)*64 + lane];
        short8 b0 = B8[((size_t)nt0*KT + kt)*64 + lane];
        short8 b1 = B8[((size_t)(nt0+1)*KT + kt)*64 + lane];
        acc0 = __builtin_amdgcn_mfma_f32_16x16x32_bf16(a, b0, acc0, 0,0,0);
        acc1 = __builtin_amdgcn_mfma_f32_16x16x32_bf16(a, b1, acc1, 0,0,0);
    }
    const int r0 = mtile*16 + (lane>>4)*4;
    const int c0 = nt0*16 + (lane&15);
    const float bb0 = bias[c0], bb1 = bias[c0+16];
    #pragma unroll
    for (int i=0;i<4;++i){
        C[(size_t)(r0+i)*1536 + c0]    = acc0[i] + bb0;
        C[(size_t)(r0+i)*1536 + c0+16] = acc1[i] + bb1;
    }
}

// ============ fused GRU + pair entanglement mixing ============
__global__ __launch_bounds__(512) void k_mix(const float* __restrict__ GI,
        const float* __restrict__ GH, const float* __restrict__ tension,
        const float* __restrict__ wcol, const float* __restrict__ hiddens,
        const float* __restrict__ bell, const float* __restrict__ ent,
        float* __restrict__ hmix)
{
    const int p = blockIdx.x;
    const int tid = threadIdx.x;
    const int lane = tid & 63;
    const int wv = tid >> 6;
    __shared__ __align__(16) float hi[HID], hj[HID];
    __shared__ __align__(16) float colacc[8][HID];
    {
        const int j = tid;
        const float wj0 = wcol[j], wj1 = wcol[512+j], wj2 = wcol[1024+j];
        #pragma unroll
        for (int c01=0; c01<2; ++c01){
            const int cell = 2*p + c01;
            const float tv = tension[cell];
            const float* gi = GI + (size_t)cell*1536;
            const float* gh = GH + (size_t)cell*1536;
            float rg = sigm(gi[j]      + tv*wj0 + gh[j]);
            float zg = sigm(gi[512+j]  + tv*wj1 + gh[512+j]);
            float nn = tanhf(gi[1024+j]+ tv*wj2 + rg*gh[1024+j]);
            float h  = (1.f - zg)*nn + zg*hiddens[(size_t)cell*HID + j];
            (c01 ? hj : hi)[j] = h;
        }
    }
    __syncthreads();
    const float* __restrict__ rot = bell + (size_t)p * HID * HID;
    const float e = 1.0f/(1.0f + expf(-ent[p]));
    const float one_e = 1.0f - e;
    const int c0 = lane<<2, c1 = 256 + (lane<<2);
    float hjr[8];
    #pragma unroll
    for (int k=0;k<4;++k){ hjr[k]=hj[c0+k]; hjr[4+k]=hj[c1+k]; }
    float aj[8] = {};
    #pragma unroll 2
    for (int r = wv; r < HID; r += 32) {
        const float* rp0 = rot + (size_t)r*HID;
        const float* rp1 = rot + (size_t)(r+8)*HID;
        const float* rp2 = rot + (size_t)(r+16)*HID;
        const float* rp3 = rot + (size_t)(r+24)*HID;
        float4 a0 = *(const float4*)(rp0 + c0);
        float4 a1 = *(const float4*)(rp0 + c1);
        float4 b0 = *(const float4*)(rp1 + c0);
        float4 b1 = *(const float4*)(rp1 + c1);
        float4 g0 = *(const float4*)(rp2 + c0);
        float4 g1 = *(const float4*)(rp2 + c1);
        float4 d0 = *(const float4*)(rp3 + c0);
        float4 d1 = *(const float4*)(rp3 + c1);
        float t0[8], t1[8], t2[8], t3[8];
        t0[0]=tanh3(a0.x); t0[1]=tanh3(a0.y); t0[2]=tanh3(a0.z); t0[3]=tanh3(a0.w);
        t0[4]=tanh3(a1.x); t0[5]=tanh3(a1.y); t0[6]=tanh3(a1.z); t0[7]=tanh3(a1.w);
        t1[0]=tanh3(b0.x); t1[1]=tanh3(b0.y); t1[2]=tanh3(b0.z); t1[3]=tanh3(b0.w);
        t1[4]=tanh3(b1.x); t1[5]=tanh3(b1.y); t1[6]=tanh3(b1.z); t1[7]=tanh3(b1.w);
        t2[0]=tanh3(g0.x); t2[1]=tanh3(g0.y); t2[2]=tanh3(g0.z); t2[3]=tanh3(g0.w);
        t2[4]=tanh3(g1.x); t2[5]=tanh3(g1.y); t2[6]=tanh3(g1.z); t2[7]=tanh3(g1.w);
        t3[0]=tanh3(d0.x); t3[1]=tanh3(d0.y); t3[2]=tanh3(d0.z); t3[3]=tanh3(d0.w);
        t3[4]=tanh3(d1.x); t3[5]=tanh3(d1.y); t3[6]=tanh3(d1.z); t3[7]=tanh3(d1.w);
        const float h0 = hi[r], h1 = hi[r+8], h2 = hi[r+16], h3 = hi[r+24];
        float rp_0 = 0.f, rp_1 = 0.f, rp_2 = 0.f, rp_3 = 0.f;
        #pragma unroll
        for (int k=0;k<8;++k){
            rp_0 = fmaf(t0[k], hjr[k], rp_0);
            rp_1 = fmaf(t1[k], hjr[k], rp_1);
            rp_2 = fmaf(t2[k], hjr[k], rp_2);
            rp_3 = fmaf(t3[k], hjr[k], rp_3);
            aj[k] = fmaf(t0[k], h0, fmaf(t1[k], h1, fmaf(t2[k], h2, fmaf(t3[k], h3, aj[k]))));
        }
        #pragma unroll
        for (int m=1;m<64;m<<=1){
            rp_0 += __shfl_xor(rp_0, m);
            rp_1 += __shfl_xor(rp_1, m);
            rp_2 += __shfl_xor(rp_2, m);
            rp_3 += __shfl_xor(rp_3, m);
        }
        if (lane == 0){
            float* dst = hmix + (size_t)(2*p)*HID;
            dst[r]    = one_e*h0 + e*rp_0;
            dst[r+8]  = one_e*h1 + e*rp_1;
            dst[r+16] = one_e*h2 + e*rp_2;
            dst[r+24] = one_e*h3 + e*rp_3;
        }
    }
    *(float4*)&colacc[wv][c0] = make_float4(aj[0],aj[1],aj[2],aj[3]);
    *(float4*)&colacc[wv][c1] = make_float4(aj[4],aj[5],aj[6],aj[7]);
    __syncthreads();
    float s = 0.0f;
    #pragma unroll
    for (int w=0;w<8;++w) s += colacc[w][tid];
    hmix[(size_t)(2*p+1)*HID + tid] = -(one_e*hj[tid] + e*s);
}

// ============ faction mean (32 blocks x 128 thr) ============
__global__ __launch_bounds__(128) void k_fmean(const float* __restrict__ hmix, float* __restrict__ fmean){
    int f = blockIdx.x >> 2;
    int d = (blockIdx.x & 3)*128 + threadIdx.x;
    float s = 0.0f;
    for (int c=0;c<128;++c) s += hmix[(size_t)((f<<7)+c)*HID + d];
    fmean[f*HID + d] = s*(1.0f/128.0f);
}

// ============ faction sync + debate ============
__global__ __launch_bounds__(512) void k_final_h(const float* __restrict__ hmix,
        const float* __restrict__ fmean, const int* __restrict__ stepp, float* __restrict__ hout){
    int cell = blockIdx.x, d = threadIdx.x;
    int f = cell >> 7;
    float v = 0.85f*hmix[(size_t)cell*HID + d] + 0.15f*fmean[f*HID + d];
    if (*stepp > 5 && (cell & 127) < 32){
        float g = 0.0f;
        #pragma unroll
        for (int q=0;q<8;++q) g += fmean[q*HID + d];
        g *= 0.125f;
        v = 0.85f*v + 0.15f*g;
    }
    hout[(size_t)cell*HID + d] = v;
}

// ============ softmax + copart + (last block) head: 32 blocks x 256 ============
__global__ __launch_bounds__(256) void k_softpred(const float* __restrict__ tension,
        const float* __restrict__ OUT, float* __restrict__ copart,
        const float* __restrict__ head_w, const float* __restrict__ head_b,
        int* __restrict__ counter, float* __restrict__ out)
{
    const int t = threadIdx.x;
    const int lane = t & 63, wv = t >> 6;
    __shared__ float red[4], redb[4], SS[1];
    __shared__ float wts[1024];
    float4 tv = *(const float4*)&tension[t*4];
    float m = fmaxf(fmaxf(tv.x, tv.y), fmaxf(tv.z, tv.w));
    #pragma unroll
    for (int s=1;s<64;s<<=1) m = fmaxf(m, __shfl_xor(m, s));
    if (lane==0) red[wv] = m;
    __syncthreads();
    float M = fmaxf(fmaxf(red[0],red[1]), fmaxf(red[2],red[3]));
    float e0 = expf(tv.x - M), e1 = expf(tv.y - M), e2 = expf(tv.z - M), e3 = expf(tv.w - M);
    float s2 = e0+e1+e2+e3;
    float s3 = tv.x+tv.y+tv.z+tv.w;
    #pragma unroll
    for (int s=1;s<64;s<<=1){ s2 += __shfl_xor(s2,s); s3 += __shfl_xor(s3,s); }
    if (lane==0){ red[wv]=s2; redb[wv]=s3; }
    __syncthreads();
    if (t==0){
        SS[0] = red[0]+red[1]+red[2]+red[3];
        if (blockIdx.x == 0)
            out[256] = (redb[0]+redb[1]+redb[2]+redb[3]) * (1.0f/1024.0f);  // avg_tension
    }
    __syncthreads();
    const float inv = 1.0f / SS[0];
    wts[t*4+0] = e0*inv; wts[t*4+1] = e1*inv; wts[t*4+2] = e2*inv; wts[t*4+3] = e3*inv;
    __syncthreads();
    {
        const int b = blockIdx.x;
        float s = 0.0f;
        for (int r = b*32; r < b*32+32; ++r)
            s = fmaf(wts[r], OUT[(size_t)r*ODIM + t], s);
        copart[b*ODIM + t] = s;
    }
    __threadfence();
    __shared__ int isLast;
    __syncthreads();
    if (t == 0) isLast = (atomicAdd(counter, 1) == 31);
    __syncthreads();
    if (!isLast) return;
    __threadfence();
    __shared__ float co[ODIM];
    float s = 0.0f;
    #pragma unroll
    for (int b=0;b<32;++b) s += copart[b*ODIM + t];
    co[t] = s;
    __syncthreads();
    float acc = head_b[t];
    const float4* wr = (const float4*)(head_w + (size_t)t*ODIM);
    #pragma unroll 4
    for (int c4=0;c4<64;++c4){
        float4 w4 = wr[c4];
        acc = fmaf(w4.x, co[c4*4+0], acc);
        acc = fmaf(w4.y, co[c4*4+1], acc);
        acc = fmaf(w4.z, co[c4*4+2], acc);
        acc = fmaf(w4.w, co[c4*4+3], acc);
    }
    out[t] = acc;   // pred
}

extern "C" void kernel_launch(void* const* d_in, const int* in_sizes, int n_in,
                              void* d_out, int out_size, void* d_ws, size_t ws_size,
                              hipStream_t stream)
{
    const float* x      = (const float*)d_in[0];
    const float* hiddens= (const float*)d_in[1];
    const float* W1a=(const float*)d_in[2];  const float* b1a=(const float*)d_in[3];
    const float* W2a=(const float*)d_in[4];  const float* b2a=(const float*)d_in[5];
    const float* W1g=(const float*)d_in[6];  const float* b1g=(const float*)d_in[7];
    const float* W2g=(const float*)d_in[8];  const float* b2g=(const float*)d_in[9];
    const float* w_ih=(const float*)d_in[10]; const float* w_hh=(const float*)d_in[11];
    const float* b_ih=(const float*)d_in[12]; const float* b_hh=(const float*)d_in[13];
    const float* head_w=(const float*)d_in[14]; const float* head_b=(const float*)d_in[15];
    const float* ent=(const float*)d_in[16]; const float* bell=(const float*)d_in[17];
    const int*   stepp=(const int*)d_in[18];
    float* out = (float*)d_out;

    char* wsb = (char*)d_ws;
    size_t off = 0;
    auto carve = [&](size_t bytes)->char*{ char* p = wsb + off; off += (bytes + 63) & ~(size_t)63; return p; };
    ushort_t* combf = (ushort_t*)carve((size_t)1024*768*2);
    ushort_t* hiddf = (ushort_t*)carve((size_t)1024*512*2);
    ushort_t* Wc1f  = (ushort_t*)carve((size_t)256*768*2);
    ushort_t* Wc2f  = (ushort_t*)carve((size_t)256*256*2);
    ushort_t* wihf  = (ushort_t*)carve((size_t)1536*256*2);
    ushort_t* whhf  = (ushort_t*)carve((size_t)1536*512*2);
    ushort_t* H1f   = (ushort_t*)carve((size_t)1024*256*2);
    ushort_t* Of    = (ushort_t*)carve((size_t)1024*256*2);
    float* bc1   = (float*)carve(256*4);
    float* bc2   = (float*)carve(256*4);
    float* wcol  = (float*)carve(1536*4);
    float* OUT   = (float*)carve((size_t)1024*256*4);
    float* tension=(float*)carve(1024*4);
    float* tpart = (float*)carve((size_t)8*1024*4);
    float* GI    = (float*)carve((size_t)1024*1536*4);
    float* GH    = (float*)carve((size_t)1024*1536*4);
    float* hmix  = (float*)carve((size_t)1024*512*4);
    float* fmean = (float*)carve(8*512*4);
    float* copart =(float*)carve(32*256*4);
    int*   counter=(int*)carve(64);

    k_cvt<<<5408, 64, 0, stream>>>(x, hiddens, W1a, W1g, W2a, W2g, w_ih, w_hh,
                                   b1a, b1g, b2a, b2g,
                                   Wc1f, Wc2f, wihf, whhf, combf, hiddf, bc1, bc2, wcol,
                                   counter);
    k_mmL1<<<dim3(8,16), 256, 0, stream>>>(combf, Wc1f, bc1, H1f);
    k_mmL2<<<dim3(8,16), 256, 0, stream>>>(H1f, Wc2f, bc2, OUT, Of, tpart);
    k_mm2<<<dim3(48,16,3), 256, 0, stream>>>(hiddf, whhf, b_hh, GH,
                                             Of, wihf, b_ih, GI,
                                             tpart, tension);
    k_mix<<<512, 512, 0, stream>>>(GI, GH, tension, wcol, hiddens, bell, ent, hmix);
    k_fmean<<<32, 128, 0, stream>>>(hmix, fmean);
    k_final_h<<<1024, 512, 0, stream>>>(hmix, fmean, stepp, out + 257);
    k_softpred<<<32, 256, 0, stream>>>(tension, OUT, copart, head_w, head_b, counter, out);
}